// Round 7
// baseline (788.760 us; speedup 1.0000x reference)
//
#include <hip/hip_runtime.h>

#define NN 50000
#define EE 600000
#define HH 128
#define EDD 16
#define BB 256
#define LL 5
#define NN16 (NN * 16)

typedef float f32x4 __attribute__((ext_vector_type(4)));
typedef _Float16 f16x4 __attribute__((ext_vector_type(4)));
typedef _Float16 f16x8 __attribute__((ext_vector_type(8)));

// ---------------- Weight prep: W[mat][k][n] fp32 -> frag-ordered fp16 hi/lo ----------------
__global__ __launch_bounds__(256) void wprep_k(const float* __restrict__ W,
    _Float16* __restrict__ Wh, _Float16* __restrict__ Wl, int total)
{
    int idx = blockIdx.x * 256 + threadIdx.x;
    if (idx >= total) return;
    int mat = idx >> 14;
    int r = idx & 16383;
    int j = r & 7, lane = (r >> 3) & 63, ks = (r >> 9) & 3, ntw = (r >> 11) & 7;
    int lm = lane & 15, quad = lane >> 4;
    int n = (ntw >> 1) * 32 + (ntw & 1) * 16 + lm;
    int k = ks * 32 + quad * 8 + j;
    float w = W[(mat << 14) + (k << 7) + n];
    _Float16 h = (_Float16)w;
    Wh[idx] = h;
    Wl[idx] = (_Float16)(w - (float)h);
}

// ---------------- x -> fp16 (one-time) ----------------
__global__ __launch_bounds__(256) void xprep_k(const float* __restrict__ x,
    _Float16* __restrict__ X)
{
    int i = blockIdx.x * 256 + threadIdx.x;
    if (i >= NN * 32) return;
    float4 v = ((const float4*)x)[i];
    f16x4 o;
    o[0] = (_Float16)v.x; o[1] = (_Float16)v.y; o[2] = (_Float16)v.z; o[3] = (_Float16)v.w;
    ((f16x4*)X)[i] = o;
}

// ---------------- shared GEMM helpers ----------------
__device__ __forceinline__ void stage_A16(const _Float16* __restrict__ Ag, int M, int brow,
    int tid, _Float16* __restrict__ As)
{
    const int r = tid >> 2, cg = tid & 3;
    const int grow = brow + r;
    _Float16* p = As + r * 136 + cg * 32;
    if (grow < M) {
        const f16x8* s = (const f16x8*)(Ag + (size_t)grow * 128 + cg * 32);
#pragma unroll
        for (int i = 0; i < 4; ++i) ((f16x8*)p)[i] = s[i];
    } else {
        f16x8 z = (f16x8)(_Float16)0;
#pragma unroll
        for (int i = 0; i < 4; ++i) ((f16x8*)p)[i] = z;
    }
}

__device__ __forceinline__ void mfma_stage16(
    const _Float16* __restrict__ As,
    const _Float16* __restrict__ Wh, const _Float16* __restrict__ Wl,
    int wn, int lm, int quad, int lane, f32x4 acc[4][2])
{
    f16x8 Bh[2][4], Bl[2][4];
#pragma unroll
    for (int nt = 0; nt < 2; ++nt)
#pragma unroll
        for (int ks = 0; ks < 4; ++ks) {
            int fi = ((((wn * 2 + nt) * 4) + ks) * 64 + lane) * 8;
            Bh[nt][ks] = *(const f16x8*)(Wh + fi);
            Bl[nt][ks] = *(const f16x8*)(Wl + fi);
        }
#pragma unroll
    for (int ks = 0; ks < 4; ++ks) {
        f16x8 a[4];
#pragma unroll
        for (int mt = 0; mt < 4; ++mt) {
            int off = (mt * 16 + lm) * 136 + ks * 32 + quad * 8;
            a[mt] = *(const f16x8*)(As + off);
        }
#pragma unroll
        for (int mt = 0; mt < 4; ++mt)
#pragma unroll
            for (int nt = 0; nt < 2; ++nt) {
                acc[mt][nt] = __builtin_amdgcn_mfma_f32_16x16x32_f16(a[mt], Bh[nt][ks], acc[mt][nt], 0, 0, 0);
                acc[mt][nt] = __builtin_amdgcn_mfma_f32_16x16x32_f16(a[mt], Bl[nt][ks], acc[mt][nt], 0, 0, 0);
            }
    }
}

__device__ __forceinline__ void store_f16(const _Float16* __restrict__ Fo,
    _Float16* __restrict__ out, int M, int brow, int tid)
{
    const int r = tid >> 2, cg = tid & 3;
    const int grow = brow + r;
    if (grow >= M) return;
    const f16x8* src = (const f16x8*)(Fo + r * 136 + cg * 32);
    f16x8* dst = (f16x8*)(out + (size_t)grow * 128 + cg * 32);
#pragma unroll
    for (int i = 0; i < 4; ++i) dst[i] = src[i];
}

// ---------------- node encode: h = fp16(A @ W + b + vn[batch]) ----------------
__global__ __launch_bounds__(256) void gemm_node_k(
    const _Float16* __restrict__ Ag,
    const _Float16* __restrict__ Wh, const _Float16* __restrict__ Wl,
    const float* __restrict__ bias, _Float16* __restrict__ out, int M,
    const float* __restrict__ vn, const int* __restrict__ batch)
{
    __shared__ __align__(16) _Float16 smem[64 * 136];
    const int tid = threadIdx.x, brow = blockIdx.x * 64;

    stage_A16(Ag, M, brow, tid, smem);
    __syncthreads();

    const int lane = tid & 63, wn = tid >> 6, lm = lane & 15, quad = lane >> 4;
    f32x4 acc[4][2];
#pragma unroll
    for (int mt = 0; mt < 4; ++mt) { acc[mt][0] = (f32x4)(0.f); acc[mt][1] = (f32x4)(0.f); }
    mfma_stage16(smem, Wh, Wl, wn, lm, quad, lane, acc);
    __syncthreads();

    const int colb = wn * 32 + lm;
    const float b0 = bias[colb], b1 = bias[colb + 16];
#pragma unroll
    for (int mt = 0; mt < 4; ++mt) {
#pragma unroll
        for (int r = 0; r < 4; ++r) {
            int trow = mt * 16 + quad * 4 + r;
            int grow = brow + trow;
            int bg = batch[grow < M ? grow : M - 1];
            const float* vrow = vn + (size_t)bg * 128;
            smem[trow * 136 + colb]      = (_Float16)(acc[mt][0][r] + b0 + vrow[colb]);
            smem[trow * 136 + colb + 16] = (_Float16)(acc[mt][1][r] + b1 + vrow[colb + 16]);
        }
    }
    __syncthreads();
    store_f16(smem, out, M, brow, tid);
}

// ---------------- fused aggregate + MLP + pooled partial sums ----------------
// As[node,:] = fp16( sum_p h[csr_src[p],:] + aggE[node]@eW + deg*eb )
// X = fp16(relu(relu(As@W1+b1)@W2+b2)); pooled[g,:] += per-block segment sums of X
__global__ __launch_bounds__(256) void agg_mlp_k(
    const _Float16* __restrict__ h, const float* __restrict__ aggE,
    const float* __restrict__ eW, const float* __restrict__ eb,
    const int* __restrict__ rowstart, const int* __restrict__ csr_src,
    const _Float16* __restrict__ W1h, const _Float16* __restrict__ W1l, const float* __restrict__ b1,
    const _Float16* __restrict__ W2h, const _Float16* __restrict__ W2l, const float* __restrict__ b2,
    _Float16* __restrict__ X, float* __restrict__ pooled,
    const int* __restrict__ batch, int M)
{
    __shared__ __align__(16) _Float16 As[64 * 136];
    __shared__ float eWs[16 * 128];
    __shared__ float ebs[128];
    const int tid = threadIdx.x, brow = blockIdx.x * 64;

#pragma unroll
    for (int t = 0; t < 2; ++t) {
        int li = (tid + t * 256) * 4;
        *(float4*)(&eWs[li]) = *(const float4*)(eW + li);
    }
    if (tid < 32) *(float4*)(&ebs[tid * 4]) = *(const float4*)(eb + tid * 4);
    __syncthreads();

    // ---- aggregation phase: 8 groups of 32 lanes, each does 8 nodes ----
    {
        const int lane32 = tid & 31, grp = tid >> 5;
        const f16x4* h4 = (const f16x4*)h;
        const float4 b4 = *(const float4*)(&ebs[lane32 * 4]);
        for (int i = 0; i < 8; ++i) {
            const int nl = grp * 8 + i;
            const int node = brow + nl;
            float4 acc = make_float4(0.f, 0.f, 0.f, 0.f);
            if (node < M) {
                const int s = rowstart[node], e = rowstart[node + 1];
                int p = s;
                for (; p + 4 <= e; p += 4) {
                    int s0 = csr_src[p], s1 = csr_src[p + 1], s2 = csr_src[p + 2], s3 = csr_src[p + 3];
                    f16x4 v0 = h4[(size_t)s0 * 32 + lane32];
                    f16x4 v1 = h4[(size_t)s1 * 32 + lane32];
                    f16x4 v2 = h4[(size_t)s2 * 32 + lane32];
                    f16x4 v3 = h4[(size_t)s3 * 32 + lane32];
                    acc.x += (float)v0[0] + (float)v1[0] + (float)v2[0] + (float)v3[0];
                    acc.y += (float)v0[1] + (float)v1[1] + (float)v2[1] + (float)v3[1];
                    acc.z += (float)v0[2] + (float)v1[2] + (float)v2[2] + (float)v3[2];
                    acc.w += (float)v0[3] + (float)v1[3] + (float)v2[3] + (float)v3[3];
                }
                for (; p < e; ++p) {
                    f16x4 v = h4[(size_t)csr_src[p] * 32 + lane32];
                    acc.x += (float)v[0]; acc.y += (float)v[1]; acc.z += (float)v[2]; acc.w += (float)v[3];
                }
                const float degf = (float)(e - s);
                const float* ae = aggE + (size_t)node * 16;
                float4 et = make_float4(degf * b4.x, degf * b4.y, degf * b4.z, degf * b4.w);
#pragma unroll
                for (int k = 0; k < 16; ++k) {
                    float a = ae[k];
                    float4 w = *(const float4*)(&eWs[k * 128 + lane32 * 4]);
                    et.x = fmaf(a, w.x, et.x);
                    et.y = fmaf(a, w.y, et.y);
                    et.z = fmaf(a, w.z, et.z);
                    et.w = fmaf(a, w.w, et.w);
                }
                acc.x += et.x; acc.y += et.y; acc.z += et.z; acc.w += et.w;
            }
            f16x4 o;
            o[0] = (_Float16)acc.x; o[1] = (_Float16)acc.y; o[2] = (_Float16)acc.z; o[3] = (_Float16)acc.w;
            *(f16x4*)(&As[nl * 136 + lane32 * 4]) = o;
        }
    }
    __syncthreads();

    // ---- MLP stage 1 ----
    const int lane = tid & 63, wn = tid >> 6, lm = lane & 15, quad = lane >> 4;
    const int colb = wn * 32 + lm;
    f32x4 acc[4][2];
#pragma unroll
    for (int mt = 0; mt < 4; ++mt) { acc[mt][0] = (f32x4)(0.f); acc[mt][1] = (f32x4)(0.f); }
    mfma_stage16(As, W1h, W1l, wn, lm, quad, lane, acc);
    __syncthreads();
    {
        const float c0 = b1[colb], c1 = b1[colb + 16];
#pragma unroll
        for (int mt = 0; mt < 4; ++mt) {
#pragma unroll
            for (int r = 0; r < 4; ++r) {
                int trow = mt * 16 + quad * 4 + r;
                As[trow * 136 + colb]      = (_Float16)fmaxf(acc[mt][0][r] + c0, 0.f);
                As[trow * 136 + colb + 16] = (_Float16)fmaxf(acc[mt][1][r] + c1, 0.f);
            }
        }
    }
    __syncthreads();

    // ---- MLP stage 2 ----
#pragma unroll
    for (int mt = 0; mt < 4; ++mt) { acc[mt][0] = (f32x4)(0.f); acc[mt][1] = (f32x4)(0.f); }
    mfma_stage16(As, W2h, W2l, wn, lm, quad, lane, acc);
    __syncthreads();
    {
        const float d0 = b2[colb], d1 = b2[colb + 16];
#pragma unroll
        for (int mt = 0; mt < 4; ++mt) {
#pragma unroll
            for (int r = 0; r < 4; ++r) {
                int trow = mt * 16 + quad * 4 + r;
                As[trow * 136 + colb]      = (_Float16)fmaxf(acc[mt][0][r] + d0, 0.f);
                As[trow * 136 + colb + 16] = (_Float16)fmaxf(acc[mt][1][r] + d1, 0.f);
            }
        }
    }
    __syncthreads();
    store_f16(As, X, M, brow, tid);

    // ---- pooled partial sums (segmented by sorted batch id) ----
    {
        const int c = tid & 127, half = tid >> 7;
        const int row0 = half * 32;
        float sum = 0.f;
        int curg = -1;
        for (int r2 = 0; r2 < 32; ++r2) {
            int grow = brow + row0 + r2;
            if (grow >= M) break;
            int g = batch[grow];
            if (g != curg) {
                if (curg >= 0) atomicAdd(&pooled[curg * 128 + c], sum);
                curg = g; sum = 0.f;
            }
            sum += (float)As[(row0 + r2) * 136 + c];
        }
        if (curg >= 0) atomicAdd(&pooled[curg * 128 + c], sum);
    }
}

// ---------------- aggE[n,16] = sum of eattr over in-edges ----------------
__global__ __launch_bounds__(256) void aggE_k(
    const float* __restrict__ eattr, const int* __restrict__ rowstart,
    const int2* __restrict__ csr_pair, float* __restrict__ aggE, int n)
{
    const int lane = threadIdx.x & 15;
    const int node = blockIdx.x * 16 + (threadIdx.x >> 4);
    if (node >= n) return;
    const int s = rowstart[node], e = rowstart[node + 1];
    float acc = 0.f;
    for (int p = s; p < e; ++p)
        acc += eattr[(size_t)csr_pair[p].y * 16 + lane];
    aggE[(size_t)node * 16 + lane] = acc;
}

// ---------------- VN update from pooled sums (also clears pooled) ----------------
__global__ __launch_bounds__(128) void vn_update_k(
    float* __restrict__ pooled, const int* __restrict__ gstart,
    const float* __restrict__ W0, const float* __restrict__ b0,
    const float* __restrict__ W1, const float* __restrict__ b1,
    float* __restrict__ vn)
{
    __shared__ float p[128], q[128];
    const int g = blockIdx.x, t = threadIdx.x;
    float cnt = (float)(gstart[g + 1] - gstart[g]);
    if (cnt < 1.f) cnt = 1.f;
    p[t] = pooled[g * 128 + t] / cnt;
    pooled[g * 128 + t] = 0.f;     // clear for next layer's accumulation
    __syncthreads();
    float a0 = b0[t];
    for (int k = 0; k < 128; ++k) a0 = fmaf(p[k], W0[k * 128 + t], a0);
    q[t] = fmaxf(a0, 0.f);
    __syncthreads();
    float a1 = b1[t];
    for (int k = 0; k < 128; ++k) a1 = fmaf(q[k], W1[k * 128 + t], a1);
    vn[g * 128 + t] += fmaxf(a1, 0.f);
}

// ---------------- final classifier from pooled sums ----------------
__global__ __launch_bounds__(128) void fc_k(
    const float* __restrict__ pooled, const int* __restrict__ gstart,
    const float* __restrict__ W, const float* __restrict__ b,
    float* __restrict__ out)
{
    __shared__ float p[128];
    const int g = blockIdx.x, t = threadIdx.x;
    float cnt = (float)(gstart[g + 1] - gstart[g]);
    if (cnt < 1.f) cnt = 1.f;
    p[t] = pooled[g * 128 + t] / cnt;
    __syncthreads();
    float acc = b[t];
    for (int k = 0; k < 128; ++k) acc = fmaf(p[k], W[k * 128 + t], acc);
    out[g * 128 + t] = acc;
}

// ---------------- CSR build helpers ----------------
__global__ void histp_k(const int* __restrict__ idx, int n, int* __restrict__ cntp)
{
    int i = blockIdx.x * 256 + threadIdx.x;
    if (i < n) atomicAdd(&cntp[(blockIdx.x & 3) * NN16 + (idx[i] << 4)], 1);
}

__global__ void scan_deg_k(const int* __restrict__ degp, int n, int* __restrict__ out, int* __restrict__ bsum)
{
    __shared__ int s[256];
    int gid = blockIdx.x * 256 + threadIdx.x;
    int v = 0;
    if (gid < n) {
        int o = gid << 4;
        v = degp[o] + degp[NN16 + o] + degp[2 * NN16 + o] + degp[3 * NN16 + o];
    }
    s[threadIdx.x] = v;
    __syncthreads();
    for (int off = 1; off < 256; off <<= 1) {
        int t = (threadIdx.x >= off) ? s[threadIdx.x - off] : 0;
        __syncthreads();
        s[threadIdx.x] += t;
        __syncthreads();
    }
    int incl = s[threadIdx.x];
    if (gid < n) out[gid] = incl - v;
    if (bsum != nullptr && threadIdx.x == 255) bsum[blockIdx.x] = incl;
}

__global__ void scan_k(const int* __restrict__ in, int n, int* __restrict__ out, int* __restrict__ bsum)
{
    __shared__ int s[256];
    int gid = blockIdx.x * 256 + threadIdx.x;
    int v = (gid < n) ? in[gid] : 0;
    s[threadIdx.x] = v;
    __syncthreads();
    for (int off = 1; off < 256; off <<= 1) {
        int t = (threadIdx.x >= off) ? s[threadIdx.x - off] : 0;
        __syncthreads();
        s[threadIdx.x] += t;
        __syncthreads();
    }
    int incl = s[threadIdx.x];
    if (gid < n) out[gid] = incl - v;
    if (bsum != nullptr && threadIdx.x == 255) bsum[blockIdx.x] = incl;
}

__global__ void addoff_k(int* __restrict__ data, const int* __restrict__ boff, int n, int total)
{
    int i = blockIdx.x * 256 + threadIdx.x;
    if (i < n) data[i] += boff[blockIdx.x];
    if (i == 0) data[n] = total;
}

__global__ void curinit_k(const int* __restrict__ rowstart, int* __restrict__ cursorp)
{
    int i = blockIdx.x * 256 + threadIdx.x;
    if (i < NN) cursorp[i << 4] = rowstart[i];
}

__global__ void fill_k(const int* __restrict__ dst, const int* __restrict__ src, int n,
                       int* __restrict__ cursorp, int2* __restrict__ csr_pair)
{
    int e = blockIdx.x * 256 + threadIdx.x;
    if (e < n) {
        int slot = atomicAdd(&cursorp[dst[e] << 4], 1);
        int2 pr; pr.x = src[e]; pr.y = e;
        csr_pair[slot] = pr;
    }
}

__global__ void split_k(const int2* __restrict__ csr_pair, int* __restrict__ csr_src, int n)
{
    int i = blockIdx.x * 256 + threadIdx.x;
    if (i < n) csr_src[i] = csr_pair[i].x;
}

__global__ void gstart_k(const int* __restrict__ batch, int* __restrict__ gstart)
{
    int b = blockIdx.x * 64 + threadIdx.x;
    if (b > BB) return;
    if (b == BB) { gstart[BB] = NN; return; }
    int lo = 0, hi = NN;
    while (lo < hi) {
        int mid = (lo + hi) >> 1;
        if (batch[mid] < b) lo = mid + 1; else hi = mid;
    }
    gstart[b] = lo;
}

__global__ void vninit_k(const float* __restrict__ vninit, float* __restrict__ vn, float* __restrict__ pooled)
{
    int i = blockIdx.x * 256 + threadIdx.x;
    vn[i] = vninit[i & 127];
    pooled[i] = 0.f;
}

// ---------------- Launch ----------------
extern "C" void kernel_launch(void* const* d_in, const int* in_sizes, int n_in,
                              void* d_out, int out_size, void* d_ws, size_t ws_size,
                              hipStream_t stream)
{
    (void)in_sizes; (void)n_in; (void)out_size; (void)ws_size;
    const float* x       = (const float*)d_in[0];
    const float* eattr   = (const float*)d_in[1];
    const float* node_W  = (const float*)d_in[2];
    const float* node_b  = (const float*)d_in[3];
    const float* edge_W  = (const float*)d_in[4];
    const float* edge_b  = (const float*)d_in[5];
    const float* mlp1_W  = (const float*)d_in[6];
    const float* mlp1_b  = (const float*)d_in[7];
    const float* mlp2_W  = (const float*)d_in[8];
    const float* mlp2_b  = (const float*)d_in[9];
    const float* vn_w0   = (const float*)d_in[10];
    const float* vn_b0   = (const float*)d_in[11];
    const float* vn_w1   = (const float*)d_in[12];
    const float* vn_b1   = (const float*)d_in[13];
    const float* fc_W    = (const float*)d_in[14];
    const float* fc_b    = (const float*)d_in[15];
    const float* vn_init = (const float*)d_in[16];
    const int*   eidx    = (const int*)d_in[17];
    const int*   batch   = (const int*)d_in[18];
    const int* srcv = eidx;
    const int* dstv = eidx + EE;

    char* wp = (char*)d_ws;
    auto alloc = [&](size_t bytes) -> void* {
        void* p = (void*)wp;
        wp += (bytes + 255) & ~(size_t)255;
        return p;
    };
    _Float16* X0  = (_Float16*)alloc((size_t)NN * HH * 2);
    _Float16* X   = (_Float16*)alloc((size_t)NN * HH * 2);
    _Float16* h16 = (_Float16*)alloc((size_t)NN * HH * 2);
    float* aggE   = (float*)alloc((size_t)NN * EDD * 4);
    float* vn     = (float*)alloc((size_t)BB * HH * 4);
    float* pooled = (float*)alloc((size_t)BB * HH * 4);
    int* degp     = (int*)alloc((size_t)4 * NN16 * 4);
    int* rowstart = (int*)alloc((size_t)(NN + 1) * 4);
    int* cursorp  = (int*)alloc((size_t)NN16 * 4);
    int2* csr_pair= (int2*)alloc((size_t)EE * 8);
    int* csr_src  = (int*)alloc((size_t)EE * 4);
    int* bsum     = (int*)alloc(256 * 4);
    int* boff     = (int*)alloc(256 * 4);
    int* gstart   = (int*)alloc((size_t)(BB + 1) * 4);
    _Float16* WtN_h = (_Float16*)alloc((size_t)5 * 16384 * 2);
    _Float16* WtN_l = (_Float16*)alloc((size_t)5 * 16384 * 2);
    _Float16* Wt1_h = (_Float16*)alloc((size_t)5 * 16384 * 2);
    _Float16* Wt1_l = (_Float16*)alloc((size_t)5 * 16384 * 2);
    _Float16* Wt2_h = (_Float16*)alloc((size_t)5 * 16384 * 2);
    _Float16* Wt2_l = (_Float16*)alloc((size_t)5 * 16384 * 2);

    hipMemsetAsync(degp, 0, (size_t)4 * NN16 * 4, stream);

    histp_k<<<(EE + 255) / 256, 256, 0, stream>>>(dstv, EE, degp);

    const int NB1 = (NN + 255) / 256;
    scan_deg_k<<<NB1, 256, 0, stream>>>(degp, NN, rowstart, bsum);
    scan_k<<<1, 256, 0, stream>>>(bsum, NB1, boff, nullptr);
    addoff_k<<<NB1, 256, 0, stream>>>(rowstart, boff, NN, EE);
    curinit_k<<<NB1, 256, 0, stream>>>(rowstart, cursorp);
    fill_k<<<(EE + 255) / 256, 256, 0, stream>>>(dstv, srcv, EE, cursorp, csr_pair);
    split_k<<<(EE + 255) / 256, 256, 0, stream>>>(csr_pair, csr_src, EE);

    gstart_k<<<5, 64, 0, stream>>>(batch, gstart);

    aggE_k<<<(NN + 15) / 16, 256, 0, stream>>>(eattr, rowstart, csr_pair, aggE, NN);
    vninit_k<<<(BB * HH) / 256, 256, 0, stream>>>(vn_init, vn, pooled);
    xprep_k<<<(NN * 32 + 255) / 256, 256, 0, stream>>>(x, X0);

    wprep_k<<<(5 * 16384 + 255) / 256, 256, 0, stream>>>(node_W, WtN_h, WtN_l, 5 * 16384);
    wprep_k<<<(5 * 16384 + 255) / 256, 256, 0, stream>>>(mlp1_W, Wt1_h, Wt1_l, 5 * 16384);
    wprep_k<<<(5 * 16384 + 255) / 256, 256, 0, stream>>>(mlp2_W, Wt2_h, Wt2_l, 5 * 16384);

    const int GN = (NN + 63) / 64;
    const _Float16* xin = X0;
    for (int l = 0; l < LL; ++l) {
        gemm_node_k<<<GN, 256, 0, stream>>>(xin,
                                            WtN_h + (size_t)l * 16384, WtN_l + (size_t)l * 16384,
                                            node_b + (size_t)l * HH, h16, NN, vn, batch);
        agg_mlp_k<<<GN, 256, 0, stream>>>(h16, aggE, edge_W + (size_t)l * EDD * HH,
                                          edge_b + (size_t)l * HH, rowstart, csr_src,
                                          Wt1_h + (size_t)l * 16384, Wt1_l + (size_t)l * 16384, mlp1_b + (size_t)l * HH,
                                          Wt2_h + (size_t)l * 16384, Wt2_l + (size_t)l * 16384, mlp2_b + (size_t)l * HH,
                                          X, pooled, batch, NN);
        if (l < LL - 1)
            vn_update_k<<<BB, 128, 0, stream>>>(pooled, gstart, vn_w0, vn_b0, vn_w1, vn_b1, vn);
        xin = X;
    }
    fc_k<<<BB, 128, 0, stream>>>(pooled, gstart, fc_W, fc_b, (float*)d_out);
}

// Round 8
// 596.293 us; speedup vs baseline: 1.3228x; 1.3228x over previous
//
#include <hip/hip_runtime.h>

#define NN 50000
#define EE 600000
#define HH 128
#define EDD 16
#define BB 256
#define LL 5
#define NN16 (NN * 16)

typedef float f32x4 __attribute__((ext_vector_type(4)));
typedef _Float16 f16x4 __attribute__((ext_vector_type(4)));
typedef _Float16 f16x8 __attribute__((ext_vector_type(8)));

// ---------------- Weight prep: W[mat][k][n] fp32 -> frag-ordered fp16 hi/lo ----------------
__global__ __launch_bounds__(256) void wprep_k(const float* __restrict__ W,
    _Float16* __restrict__ Wh, _Float16* __restrict__ Wl, int total)
{
    int idx = blockIdx.x * 256 + threadIdx.x;
    if (idx >= total) return;
    int mat = idx >> 14;
    int r = idx & 16383;
    int j = r & 7, lane = (r >> 3) & 63, ks = (r >> 9) & 3, ntw = (r >> 11) & 7;
    int lm = lane & 15, quad = lane >> 4;
    int n = (ntw >> 1) * 32 + (ntw & 1) * 16 + lm;
    int k = ks * 32 + quad * 8 + j;
    float w = W[(mat << 14) + (k << 7) + n];
    _Float16 h = (_Float16)w;
    Wh[idx] = h;
    Wl[idx] = (_Float16)(w - (float)h);
}

// ---------------- x -> fp16 (one-time) ----------------
__global__ __launch_bounds__(256) void xprep_k(const float* __restrict__ x,
    _Float16* __restrict__ X)
{
    int i = blockIdx.x * 256 + threadIdx.x;
    if (i >= NN * 32) return;
    float4 v = ((const float4*)x)[i];
    f16x4 o;
    o[0] = (_Float16)v.x; o[1] = (_Float16)v.y; o[2] = (_Float16)v.z; o[3] = (_Float16)v.w;
    ((f16x4*)X)[i] = o;
}

// ---------------- shared GEMM helpers ----------------
__device__ __forceinline__ void stage_A16(const _Float16* __restrict__ Ag, int M, int brow,
    int tid, _Float16* __restrict__ As)
{
    const int r = tid >> 2, cg = tid & 3;
    const int grow = brow + r;
    _Float16* p = As + r * 136 + cg * 32;
    if (grow < M) {
        const f16x8* s = (const f16x8*)(Ag + (size_t)grow * 128 + cg * 32);
#pragma unroll
        for (int i = 0; i < 4; ++i) ((f16x8*)p)[i] = s[i];
    } else {
        f16x8 z = (f16x8)(_Float16)0;
#pragma unroll
        for (int i = 0; i < 4; ++i) ((f16x8*)p)[i] = z;
    }
}

__device__ __forceinline__ void mfma_stage16(
    const _Float16* __restrict__ As,
    const _Float16* __restrict__ Wh, const _Float16* __restrict__ Wl,
    int wn, int lm, int quad, int lane, f32x4 acc[4][2])
{
    f16x8 Bh[2][4], Bl[2][4];
#pragma unroll
    for (int nt = 0; nt < 2; ++nt)
#pragma unroll
        for (int ks = 0; ks < 4; ++ks) {
            int fi = ((((wn * 2 + nt) * 4) + ks) * 64 + lane) * 8;
            Bh[nt][ks] = *(const f16x8*)(Wh + fi);
            Bl[nt][ks] = *(const f16x8*)(Wl + fi);
        }
#pragma unroll
    for (int ks = 0; ks < 4; ++ks) {
        f16x8 a[4];
#pragma unroll
        for (int mt = 0; mt < 4; ++mt) {
            int off = (mt * 16 + lm) * 136 + ks * 32 + quad * 8;
            a[mt] = *(const f16x8*)(As + off);
        }
#pragma unroll
        for (int mt = 0; mt < 4; ++mt)
#pragma unroll
            for (int nt = 0; nt < 2; ++nt) {
                acc[mt][nt] = __builtin_amdgcn_mfma_f32_16x16x32_f16(a[mt], Bh[nt][ks], acc[mt][nt], 0, 0, 0);
                acc[mt][nt] = __builtin_amdgcn_mfma_f32_16x16x32_f16(a[mt], Bl[nt][ks], acc[mt][nt], 0, 0, 0);
            }
    }
}

__device__ __forceinline__ void store_f16(const _Float16* __restrict__ Fo,
    _Float16* __restrict__ out, int M, int brow, int tid)
{
    const int r = tid >> 2, cg = tid & 3;
    const int grow = brow + r;
    if (grow >= M) return;
    const f16x8* src = (const f16x8*)(Fo + r * 136 + cg * 32);
    f16x8* dst = (f16x8*)(out + (size_t)grow * 128 + cg * 32);
#pragma unroll
    for (int i = 0; i < 4; ++i) dst[i] = src[i];
}

// ---------------- node encode: h = fp16(A @ W + b + vn[batch]) ----------------
__global__ __launch_bounds__(256) void gemm_node_k(
    const _Float16* __restrict__ Ag,
    const _Float16* __restrict__ Wh, const _Float16* __restrict__ Wl,
    const float* __restrict__ bias, _Float16* __restrict__ out, int M,
    const float* __restrict__ vn, const int* __restrict__ batch)
{
    __shared__ __align__(16) _Float16 smem[64 * 136];
    const int tid = threadIdx.x, brow = blockIdx.x * 64;

    stage_A16(Ag, M, brow, tid, smem);
    __syncthreads();

    const int lane = tid & 63, wn = tid >> 6, lm = lane & 15, quad = lane >> 4;
    f32x4 acc[4][2];
#pragma unroll
    for (int mt = 0; mt < 4; ++mt) { acc[mt][0] = (f32x4)(0.f); acc[mt][1] = (f32x4)(0.f); }
    mfma_stage16(smem, Wh, Wl, wn, lm, quad, lane, acc);
    __syncthreads();

    const int colb = wn * 32 + lm;
    const float b0 = bias[colb], b1 = bias[colb + 16];
#pragma unroll
    for (int mt = 0; mt < 4; ++mt) {
#pragma unroll
        for (int r = 0; r < 4; ++r) {
            int trow = mt * 16 + quad * 4 + r;
            int grow = brow + trow;
            int bg = batch[grow < M ? grow : M - 1];
            const float* vrow = vn + (size_t)bg * 128;
            smem[trow * 136 + colb]      = (_Float16)(acc[mt][0][r] + b0 + vrow[colb]);
            smem[trow * 136 + colb + 16] = (_Float16)(acc[mt][1][r] + b1 + vrow[colb + 16]);
        }
    }
    __syncthreads();
    store_f16(smem, out, M, brow, tid);
}

// ---------------- fused MLP + pooled partials: X = fp16(relu(relu(A@W1+b1)@W2+b2)) ----------------
__global__ __launch_bounds__(256) void gemm_mlp_k(
    const _Float16* __restrict__ Ag,
    const _Float16* __restrict__ W1h, const _Float16* __restrict__ W1l, const float* __restrict__ b1,
    const _Float16* __restrict__ W2h, const _Float16* __restrict__ W2l, const float* __restrict__ b2,
    _Float16* __restrict__ X, float* __restrict__ pooled,
    const int* __restrict__ batch, int M)
{
    __shared__ __align__(16) _Float16 smem[64 * 136];
    const int tid = threadIdx.x, brow = blockIdx.x * 64;

    stage_A16(Ag, M, brow, tid, smem);
    __syncthreads();

    const int lane = tid & 63, wn = tid >> 6, lm = lane & 15, quad = lane >> 4;
    const int colb = wn * 32 + lm;

    f32x4 acc[4][2];
#pragma unroll
    for (int mt = 0; mt < 4; ++mt) { acc[mt][0] = (f32x4)(0.f); acc[mt][1] = (f32x4)(0.f); }
    mfma_stage16(smem, W1h, W1l, wn, lm, quad, lane, acc);
    __syncthreads();

    {
        const float c0 = b1[colb], c1 = b1[colb + 16];
#pragma unroll
        for (int mt = 0; mt < 4; ++mt) {
#pragma unroll
            for (int r = 0; r < 4; ++r) {
                int trow = mt * 16 + quad * 4 + r;
                smem[trow * 136 + colb]      = (_Float16)fmaxf(acc[mt][0][r] + c0, 0.f);
                smem[trow * 136 + colb + 16] = (_Float16)fmaxf(acc[mt][1][r] + c1, 0.f);
            }
        }
    }
    __syncthreads();

#pragma unroll
    for (int mt = 0; mt < 4; ++mt) { acc[mt][0] = (f32x4)(0.f); acc[mt][1] = (f32x4)(0.f); }
    mfma_stage16(smem, W2h, W2l, wn, lm, quad, lane, acc);
    __syncthreads();

    {
        const float d0 = b2[colb], d1 = b2[colb + 16];
#pragma unroll
        for (int mt = 0; mt < 4; ++mt) {
#pragma unroll
            for (int r = 0; r < 4; ++r) {
                int trow = mt * 16 + quad * 4 + r;
                smem[trow * 136 + colb]      = (_Float16)fmaxf(acc[mt][0][r] + d0, 0.f);
                smem[trow * 136 + colb + 16] = (_Float16)fmaxf(acc[mt][1][r] + d1, 0.f);
            }
        }
    }
    __syncthreads();
    store_f16(smem, X, M, brow, tid);

    // pooled partial sums (batch sorted -> few segments per 32-row half)
    {
        const int c = tid & 127, half = tid >> 7;
        const int row0 = half * 32;
        float sum = 0.f;
        int curg = -1;
        for (int r2 = 0; r2 < 32; ++r2) {
            int grow = brow + row0 + r2;
            if (grow >= M) break;
            int g = batch[grow];
            if (g != curg) {
                if (curg >= 0) atomicAdd(&pooled[curg * 128 + c], sum);
                curg = g; sum = 0.f;
            }
            sum += (float)smem[(row0 + r2) * 136 + c];
        }
        if (curg >= 0) atomicAdd(&pooled[curg * 128 + c], sum);
    }
}

// ---------------- Edge aggregation: fp16 gather-sum + per-node edge term -> fp16 ----------------
__global__ __launch_bounds__(256) void aggregate_k(
    const _Float16* __restrict__ h, const float* __restrict__ aggE,
    const float* __restrict__ eW, const float* __restrict__ eb,
    const int* __restrict__ rowstart, const int2* __restrict__ csr_pair,
    _Float16* __restrict__ Ag, int n)
{
    __shared__ float eWs[16 * 128];
    __shared__ float ebs[128];
    const int tid = threadIdx.x;
#pragma unroll
    for (int t = 0; t < 2; ++t) {
        int li = (tid + t * 256) * 4;
        *(float4*)(&eWs[li]) = *(const float4*)(eW + li);
    }
    if (tid < 32) *(float4*)(&ebs[tid * 4]) = *(const float4*)(eb + tid * 4);
    __syncthreads();

    const int lane = tid & 31;
    const int node = blockIdx.x * 8 + (tid >> 5);
    if (node >= n) return;
    const int s = rowstart[node], e = rowstart[node + 1];
    const f16x4* h4 = (const f16x4*)h;

    float4 acc = make_float4(0.f, 0.f, 0.f, 0.f);
    int p = s;
    for (; p + 4 <= e; p += 4) {
        int s0 = csr_pair[p].x, s1 = csr_pair[p + 1].x, s2 = csr_pair[p + 2].x, s3 = csr_pair[p + 3].x;
        f16x4 v0 = h4[(size_t)s0 * 32 + lane];
        f16x4 v1 = h4[(size_t)s1 * 32 + lane];
        f16x4 v2 = h4[(size_t)s2 * 32 + lane];
        f16x4 v3 = h4[(size_t)s3 * 32 + lane];
        acc.x += (float)v0[0] + (float)v1[0] + (float)v2[0] + (float)v3[0];
        acc.y += (float)v0[1] + (float)v1[1] + (float)v2[1] + (float)v3[1];
        acc.z += (float)v0[2] + (float)v1[2] + (float)v2[2] + (float)v3[2];
        acc.w += (float)v0[3] + (float)v1[3] + (float)v2[3] + (float)v3[3];
    }
    for (; p < e; ++p) {
        f16x4 v = h4[(size_t)csr_pair[p].x * 32 + lane];
        acc.x += (float)v[0]; acc.y += (float)v[1]; acc.z += (float)v[2]; acc.w += (float)v[3];
    }

    const float degf = (float)(e - s);
    const float* ae = aggE + (size_t)node * 16;
    const float4 b4 = *(const float4*)(&ebs[lane * 4]);
    float4 et = make_float4(degf * b4.x, degf * b4.y, degf * b4.z, degf * b4.w);
#pragma unroll
    for (int k = 0; k < 16; ++k) {
        float a = ae[k];
        float4 w = *(const float4*)(&eWs[k * 128 + lane * 4]);
        et.x = fmaf(a, w.x, et.x);
        et.y = fmaf(a, w.y, et.y);
        et.z = fmaf(a, w.z, et.z);
        et.w = fmaf(a, w.w, et.w);
    }
    acc.x += et.x; acc.y += et.y; acc.z += et.z; acc.w += et.w;

    f16x4 o;
    o[0] = (_Float16)acc.x; o[1] = (_Float16)acc.y; o[2] = (_Float16)acc.z; o[3] = (_Float16)acc.w;
    ((f16x4*)Ag)[(size_t)node * 32 + lane] = o;
}

// ---------------- aggE[n,16] = sum of eattr over in-edges ----------------
__global__ __launch_bounds__(256) void aggE_k(
    const float* __restrict__ eattr, const int* __restrict__ rowstart,
    const int2* __restrict__ csr_pair, float* __restrict__ aggE, int n)
{
    const int lane = threadIdx.x & 15;
    const int node = blockIdx.x * 16 + (threadIdx.x >> 4);
    if (node >= n) return;
    const int s = rowstart[node], e = rowstart[node + 1];
    float acc = 0.f;
    for (int p = s; p < e; ++p)
        acc += eattr[(size_t)csr_pair[p].y * 16 + lane];
    aggE[(size_t)node * 16 + lane] = acc;
}

// ---------------- VN update from pooled sums (also clears pooled) ----------------
__global__ __launch_bounds__(128) void vn_update_k(
    float* __restrict__ pooled, const int* __restrict__ gstart,
    const float* __restrict__ W0, const float* __restrict__ b0,
    const float* __restrict__ W1, const float* __restrict__ b1,
    float* __restrict__ vn)
{
    __shared__ float p[128], q[128];
    const int g = blockIdx.x, t = threadIdx.x;
    float cnt = (float)(gstart[g + 1] - gstart[g]);
    if (cnt < 1.f) cnt = 1.f;
    p[t] = pooled[g * 128 + t] / cnt;
    pooled[g * 128 + t] = 0.f;
    __syncthreads();
    float a0 = b0[t];
    for (int k = 0; k < 128; ++k) a0 = fmaf(p[k], W0[k * 128 + t], a0);
    q[t] = fmaxf(a0, 0.f);
    __syncthreads();
    float a1 = b1[t];
    for (int k = 0; k < 128; ++k) a1 = fmaf(q[k], W1[k * 128 + t], a1);
    vn[g * 128 + t] += fmaxf(a1, 0.f);
}

// ---------------- final classifier from pooled sums ----------------
__global__ __launch_bounds__(128) void fc_k(
    const float* __restrict__ pooled, const int* __restrict__ gstart,
    const float* __restrict__ W, const float* __restrict__ b,
    float* __restrict__ out)
{
    __shared__ float p[128];
    const int g = blockIdx.x, t = threadIdx.x;
    float cnt = (float)(gstart[g + 1] - gstart[g]);
    if (cnt < 1.f) cnt = 1.f;
    p[t] = pooled[g * 128 + t] / cnt;
    __syncthreads();
    float acc = b[t];
    for (int k = 0; k < 128; ++k) acc = fmaf(p[k], W[k * 128 + t], acc);
    out[g * 128 + t] = acc;
}

// ---------------- CSR build helpers ----------------
__global__ void histp_k(const int* __restrict__ idx, int n, int* __restrict__ cntp)
{
    int i = blockIdx.x * 256 + threadIdx.x;
    if (i < n) atomicAdd(&cntp[(blockIdx.x & 3) * NN16 + (idx[i] << 4)], 1);
}

__global__ void scan_deg_k(const int* __restrict__ degp, int n, int* __restrict__ out, int* __restrict__ bsum)
{
    __shared__ int s[256];
    int gid = blockIdx.x * 256 + threadIdx.x;
    int v = 0;
    if (gid < n) {
        int o = gid << 4;
        v = degp[o] + degp[NN16 + o] + degp[2 * NN16 + o] + degp[3 * NN16 + o];
    }
    s[threadIdx.x] = v;
    __syncthreads();
    for (int off = 1; off < 256; off <<= 1) {
        int t = (threadIdx.x >= off) ? s[threadIdx.x - off] : 0;
        __syncthreads();
        s[threadIdx.x] += t;
        __syncthreads();
    }
    int incl = s[threadIdx.x];
    if (gid < n) out[gid] = incl - v;
    if (bsum != nullptr && threadIdx.x == 255) bsum[blockIdx.x] = incl;
}

__global__ void scan_k(const int* __restrict__ in, int n, int* __restrict__ out, int* __restrict__ bsum)
{
    __shared__ int s[256];
    int gid = blockIdx.x * 256 + threadIdx.x;
    int v = (gid < n) ? in[gid] : 0;
    s[threadIdx.x] = v;
    __syncthreads();
    for (int off = 1; off < 256; off <<= 1) {
        int t = (threadIdx.x >= off) ? s[threadIdx.x - off] : 0;
        __syncthreads();
        s[threadIdx.x] += t;
        __syncthreads();
    }
    int incl = s[threadIdx.x];
    if (gid < n) out[gid] = incl - v;
    if (bsum != nullptr && threadIdx.x == 255) bsum[blockIdx.x] = incl;
}

__global__ void addoff_k(int* __restrict__ data, const int* __restrict__ boff, int n, int total)
{
    int i = blockIdx.x * 256 + threadIdx.x;
    if (i < n) data[i] += boff[blockIdx.x];
    if (i == 0) data[n] = total;
}

__global__ void curinit_k(const int* __restrict__ rowstart, int* __restrict__ cursorp)
{
    int i = blockIdx.x * 256 + threadIdx.x;
    if (i < NN) cursorp[i << 4] = rowstart[i];
}

__global__ void fill_k(const int* __restrict__ dst, const int* __restrict__ src, int n,
                       int* __restrict__ cursorp, int2* __restrict__ csr_pair)
{
    int e = blockIdx.x * 256 + threadIdx.x;
    if (e < n) {
        int slot = atomicAdd(&cursorp[dst[e] << 4], 1);
        int2 pr; pr.x = src[e]; pr.y = e;
        csr_pair[slot] = pr;
    }
}

__global__ void gstart_k(const int* __restrict__ batch, int* __restrict__ gstart)
{
    int b = blockIdx.x * 64 + threadIdx.x;
    if (b > BB) return;
    if (b == BB) { gstart[BB] = NN; return; }
    int lo = 0, hi = NN;
    while (lo < hi) {
        int mid = (lo + hi) >> 1;
        if (batch[mid] < b) lo = mid + 1; else hi = mid;
    }
    gstart[b] = lo;
}

__global__ void vninit_k(const float* __restrict__ vninit, float* __restrict__ vn, float* __restrict__ pooled)
{
    int i = blockIdx.x * 256 + threadIdx.x;
    vn[i] = vninit[i & 127];
    pooled[i] = 0.f;
}

// ---------------- Launch ----------------
extern "C" void kernel_launch(void* const* d_in, const int* in_sizes, int n_in,
                              void* d_out, int out_size, void* d_ws, size_t ws_size,
                              hipStream_t stream)
{
    (void)in_sizes; (void)n_in; (void)out_size; (void)ws_size;
    const float* x       = (const float*)d_in[0];
    const float* eattr   = (const float*)d_in[1];
    const float* node_W  = (const float*)d_in[2];
    const float* node_b  = (const float*)d_in[3];
    const float* edge_W  = (const float*)d_in[4];
    const float* edge_b  = (const float*)d_in[5];
    const float* mlp1_W  = (const float*)d_in[6];
    const float* mlp1_b  = (const float*)d_in[7];
    const float* mlp2_W  = (const float*)d_in[8];
    const float* mlp2_b  = (const float*)d_in[9];
    const float* vn_w0   = (const float*)d_in[10];
    const float* vn_b0   = (const float*)d_in[11];
    const float* vn_w1   = (const float*)d_in[12];
    const float* vn_b1   = (const float*)d_in[13];
    const float* fc_W    = (const float*)d_in[14];
    const float* fc_b    = (const float*)d_in[15];
    const float* vn_init = (const float*)d_in[16];
    const int*   eidx    = (const int*)d_in[17];
    const int*   batch   = (const int*)d_in[18];
    const int* srcv = eidx;
    const int* dstv = eidx + EE;

    char* wp = (char*)d_ws;
    auto alloc = [&](size_t bytes) -> void* {
        void* p = (void*)wp;
        wp += (bytes + 255) & ~(size_t)255;
        return p;
    };
    _Float16* X0  = (_Float16*)alloc((size_t)NN * HH * 2);
    _Float16* X   = (_Float16*)alloc((size_t)NN * HH * 2);
    _Float16* Ag  = (_Float16*)alloc((size_t)NN * HH * 2);
    _Float16* h16 = (_Float16*)alloc((size_t)NN * HH * 2);
    float* aggE   = (float*)alloc((size_t)NN * EDD * 4);
    float* vn     = (float*)alloc((size_t)BB * HH * 4);
    float* pooled = (float*)alloc((size_t)BB * HH * 4);
    int* degp     = (int*)alloc((size_t)4 * NN16 * 4);
    int* rowstart = (int*)alloc((size_t)(NN + 1) * 4);
    int* cursorp  = (int*)alloc((size_t)NN16 * 4);
    int2* csr_pair= (int2*)alloc((size_t)EE * 8);
    int* bsum     = (int*)alloc(256 * 4);
    int* boff     = (int*)alloc(256 * 4);
    int* gstart   = (int*)alloc((size_t)(BB + 1) * 4);
    _Float16* WtN_h = (_Float16*)alloc((size_t)5 * 16384 * 2);
    _Float16* WtN_l = (_Float16*)alloc((size_t)5 * 16384 * 2);
    _Float16* Wt1_h = (_Float16*)alloc((size_t)5 * 16384 * 2);
    _Float16* Wt1_l = (_Float16*)alloc((size_t)5 * 16384 * 2);
    _Float16* Wt2_h = (_Float16*)alloc((size_t)5 * 16384 * 2);
    _Float16* Wt2_l = (_Float16*)alloc((size_t)5 * 16384 * 2);

    hipMemsetAsync(degp, 0, (size_t)4 * NN16 * 4, stream);

    histp_k<<<(EE + 255) / 256, 256, 0, stream>>>(dstv, EE, degp);

    const int NB1 = (NN + 255) / 256;
    scan_deg_k<<<NB1, 256, 0, stream>>>(degp, NN, rowstart, bsum);
    scan_k<<<1, 256, 0, stream>>>(bsum, NB1, boff, nullptr);
    addoff_k<<<NB1, 256, 0, stream>>>(rowstart, boff, NN, EE);
    curinit_k<<<NB1, 256, 0, stream>>>(rowstart, cursorp);
    fill_k<<<(EE + 255) / 256, 256, 0, stream>>>(dstv, srcv, EE, cursorp, csr_pair);

    gstart_k<<<5, 64, 0, stream>>>(batch, gstart);

    aggE_k<<<(NN + 15) / 16, 256, 0, stream>>>(eattr, rowstart, csr_pair, aggE, NN);
    vninit_k<<<(BB * HH) / 256, 256, 0, stream>>>(vn_init, vn, pooled);
    xprep_k<<<(NN * 32 + 255) / 256, 256, 0, stream>>>(x, X0);

    wprep_k<<<(5 * 16384 + 255) / 256, 256, 0, stream>>>(node_W, WtN_h, WtN_l, 5 * 16384);
    wprep_k<<<(5 * 16384 + 255) / 256, 256, 0, stream>>>(mlp1_W, Wt1_h, Wt1_l, 5 * 16384);
    wprep_k<<<(5 * 16384 + 255) / 256, 256, 0, stream>>>(mlp2_W, Wt2_h, Wt2_l, 5 * 16384);

    const int GN = (NN + 63) / 64;
    const _Float16* xin = X0;
    for (int l = 0; l < LL; ++l) {
        gemm_node_k<<<GN, 256, 0, stream>>>(xin,
                                            WtN_h + (size_t)l * 16384, WtN_l + (size_t)l * 16384,
                                            node_b + (size_t)l * HH, h16, NN, vn, batch);
        aggregate_k<<<(NN + 7) / 8, 256, 0, stream>>>(h16, aggE, edge_W + (size_t)l * EDD * HH,
                                                      edge_b + (size_t)l * HH, rowstart, csr_pair, Ag, NN);
        gemm_mlp_k<<<GN, 256, 0, stream>>>(Ag,
                                           Wt1_h + (size_t)l * 16384, Wt1_l + (size_t)l * 16384, mlp1_b + (size_t)l * HH,
                                           Wt2_h + (size_t)l * 16384, Wt2_l + (size_t)l * 16384, mlp2_b + (size_t)l * HH,
                                           X, pooled, batch, NN);
        if (l < LL - 1)
            vn_update_k<<<BB, 128, 0, stream>>>(pooled, gstart, vn_w0, vn_b0, vn_w1, vn_b1, vn);
        xin = X;
    }
    fc_k<<<BB, 128, 0, stream>>>(pooled, gstart, fc_W, fc_b, (float*)d_out);
}

// Round 9
// 595.430 us; speedup vs baseline: 1.3247x; 1.0014x over previous
//
#include <hip/hip_runtime.h>

#define NN 50000
#define EE 600000
#define HH 128
#define EDD 16
#define BB 256
#define LL 5
#define NN16 (NN * 16)
#define NSHADOW 8

typedef float f32x4 __attribute__((ext_vector_type(4)));
typedef _Float16 f16x4 __attribute__((ext_vector_type(4)));
typedef _Float16 f16x8 __attribute__((ext_vector_type(8)));

// ---------------- Weight prep: W[mat][k][n] fp32 -> frag-ordered fp16 hi/lo ----------------
__global__ __launch_bounds__(256) void wprep_k(const float* __restrict__ W,
    _Float16* __restrict__ Wh, _Float16* __restrict__ Wl, int total)
{
    int idx = blockIdx.x * 256 + threadIdx.x;
    if (idx >= total) return;
    int mat = idx >> 14;
    int r = idx & 16383;
    int j = r & 7, lane = (r >> 3) & 63, ks = (r >> 9) & 3, ntw = (r >> 11) & 7;
    int lm = lane & 15, quad = lane >> 4;
    int n = (ntw >> 1) * 32 + (ntw & 1) * 16 + lm;
    int k = ks * 32 + quad * 8 + j;
    float w = W[(mat << 14) + (k << 7) + n];
    _Float16 h = (_Float16)w;
    Wh[idx] = h;
    Wl[idx] = (_Float16)(w - (float)h);
}

// ---------------- x -> fp16 (one-time) ----------------
__global__ __launch_bounds__(256) void xprep_k(const float* __restrict__ x,
    _Float16* __restrict__ X)
{
    int i = blockIdx.x * 256 + threadIdx.x;
    if (i >= NN * 32) return;
    float4 v = ((const float4*)x)[i];
    f16x4 o;
    o[0] = (_Float16)v.x; o[1] = (_Float16)v.y; o[2] = (_Float16)v.z; o[3] = (_Float16)v.w;
    ((f16x4*)X)[i] = o;
}

// ---------------- shared GEMM helpers ----------------
__device__ __forceinline__ void stage_A16(const _Float16* __restrict__ Ag, int M, int brow,
    int tid, _Float16* __restrict__ As)
{
    const int r = tid >> 2, cg = tid & 3;
    const int grow = brow + r;
    _Float16* p = As + r * 136 + cg * 32;
    if (grow < M) {
        const f16x8* s = (const f16x8*)(Ag + (size_t)grow * 128 + cg * 32);
#pragma unroll
        for (int i = 0; i < 4; ++i) ((f16x8*)p)[i] = s[i];
    } else {
        f16x8 z = (f16x8)(_Float16)0;
#pragma unroll
        for (int i = 0; i < 4; ++i) ((f16x8*)p)[i] = z;
    }
}

__device__ __forceinline__ void mfma_stage16(
    const _Float16* __restrict__ As,
    const _Float16* __restrict__ Wh, const _Float16* __restrict__ Wl,
    int wn, int lm, int quad, int lane, f32x4 acc[4][2])
{
    f16x8 Bh[2][4], Bl[2][4];
#pragma unroll
    for (int nt = 0; nt < 2; ++nt)
#pragma unroll
        for (int ks = 0; ks < 4; ++ks) {
            int fi = ((((wn * 2 + nt) * 4) + ks) * 64 + lane) * 8;
            Bh[nt][ks] = *(const f16x8*)(Wh + fi);
            Bl[nt][ks] = *(const f16x8*)(Wl + fi);
        }
#pragma unroll
    for (int ks = 0; ks < 4; ++ks) {
        f16x8 a[4];
#pragma unroll
        for (int mt = 0; mt < 4; ++mt) {
            int off = (mt * 16 + lm) * 136 + ks * 32 + quad * 8;
            a[mt] = *(const f16x8*)(As + off);
        }
#pragma unroll
        for (int mt = 0; mt < 4; ++mt)
#pragma unroll
            for (int nt = 0; nt < 2; ++nt) {
                acc[mt][nt] = __builtin_amdgcn_mfma_f32_16x16x32_f16(a[mt], Bh[nt][ks], acc[mt][nt], 0, 0, 0);
                acc[mt][nt] = __builtin_amdgcn_mfma_f32_16x16x32_f16(a[mt], Bl[nt][ks], acc[mt][nt], 0, 0, 0);
            }
    }
}

__device__ __forceinline__ void store_f16(const _Float16* __restrict__ Fo,
    _Float16* __restrict__ out, int M, int brow, int tid)
{
    const int r = tid >> 2, cg = tid & 3;
    const int grow = brow + r;
    if (grow >= M) return;
    const f16x8* src = (const f16x8*)(Fo + r * 136 + cg * 32);
    f16x8* dst = (f16x8*)(out + (size_t)grow * 128 + cg * 32);
#pragma unroll
    for (int i = 0; i < 4; ++i) dst[i] = src[i];
}

// ---------------- node encode: h = fp16(A @ W + b + vn[batch]) ----------------
__global__ __launch_bounds__(256) void gemm_node_k(
    const _Float16* __restrict__ Ag,
    const _Float16* __restrict__ Wh, const _Float16* __restrict__ Wl,
    const float* __restrict__ bias, _Float16* __restrict__ out, int M,
    const float* __restrict__ vn, const int* __restrict__ batch)
{
    __shared__ __align__(16) _Float16 smem[64 * 136];
    const int tid = threadIdx.x, brow = blockIdx.x * 64;

    stage_A16(Ag, M, brow, tid, smem);
    __syncthreads();

    const int lane = tid & 63, wn = tid >> 6, lm = lane & 15, quad = lane >> 4;
    f32x4 acc[4][2];
#pragma unroll
    for (int mt = 0; mt < 4; ++mt) { acc[mt][0] = (f32x4)(0.f); acc[mt][1] = (f32x4)(0.f); }
    mfma_stage16(smem, Wh, Wl, wn, lm, quad, lane, acc);
    __syncthreads();

    const int colb = wn * 32 + lm;
    const float b0 = bias[colb], b1 = bias[colb + 16];
#pragma unroll
    for (int mt = 0; mt < 4; ++mt) {
#pragma unroll
        for (int r = 0; r < 4; ++r) {
            int trow = mt * 16 + quad * 4 + r;
            int grow = brow + trow;
            int bg = batch[grow < M ? grow : M - 1];
            const float* vrow = vn + (size_t)bg * 128;
            smem[trow * 136 + colb]      = (_Float16)(acc[mt][0][r] + b0 + vrow[colb]);
            smem[trow * 136 + colb + 16] = (_Float16)(acc[mt][1][r] + b1 + vrow[colb + 16]);
        }
    }
    __syncthreads();
    store_f16(smem, out, M, brow, tid);
}

// ---------------- fused MLP + pooled partials (shadowed): X = fp16(relu(relu(A@W1+b1)@W2+b2)) ----------------
__global__ __launch_bounds__(256) void gemm_mlp_k(
    const _Float16* __restrict__ Ag,
    const _Float16* __restrict__ W1h, const _Float16* __restrict__ W1l, const float* __restrict__ b1,
    const _Float16* __restrict__ W2h, const _Float16* __restrict__ W2l, const float* __restrict__ b2,
    _Float16* __restrict__ X, float* __restrict__ pooled8,
    const int* __restrict__ batch, int M)
{
    __shared__ __align__(16) _Float16 smem[64 * 136];
    const int tid = threadIdx.x, brow = blockIdx.x * 64;

    stage_A16(Ag, M, brow, tid, smem);
    __syncthreads();

    const int lane = tid & 63, wn = tid >> 6, lm = lane & 15, quad = lane >> 4;
    const int colb = wn * 32 + lm;

    f32x4 acc[4][2];
#pragma unroll
    for (int mt = 0; mt < 4; ++mt) { acc[mt][0] = (f32x4)(0.f); acc[mt][1] = (f32x4)(0.f); }
    mfma_stage16(smem, W1h, W1l, wn, lm, quad, lane, acc);
    __syncthreads();

    {
        const float c0 = b1[colb], c1 = b1[colb + 16];
#pragma unroll
        for (int mt = 0; mt < 4; ++mt) {
#pragma unroll
            for (int r = 0; r < 4; ++r) {
                int trow = mt * 16 + quad * 4 + r;
                smem[trow * 136 + colb]      = (_Float16)fmaxf(acc[mt][0][r] + c0, 0.f);
                smem[trow * 136 + colb + 16] = (_Float16)fmaxf(acc[mt][1][r] + c1, 0.f);
            }
        }
    }
    __syncthreads();

#pragma unroll
    for (int mt = 0; mt < 4; ++mt) { acc[mt][0] = (f32x4)(0.f); acc[mt][1] = (f32x4)(0.f); }
    mfma_stage16(smem, W2h, W2l, wn, lm, quad, lane, acc);
    __syncthreads();

    {
        const float d0 = b2[colb], d1 = b2[colb + 16];
#pragma unroll
        for (int mt = 0; mt < 4; ++mt) {
#pragma unroll
            for (int r = 0; r < 4; ++r) {
                int trow = mt * 16 + quad * 4 + r;
                smem[trow * 136 + colb]      = (_Float16)fmaxf(acc[mt][0][r] + d0, 0.f);
                smem[trow * 136 + colb + 16] = (_Float16)fmaxf(acc[mt][1][r] + d1, 0.f);
            }
        }
    }
    __syncthreads();
    store_f16(smem, X, M, brow, tid);

    // pooled partial sums into shadow copy (blockIdx&7) to cut atomic line-contention 8x
    {
        float* pooled = pooled8 + (size_t)(blockIdx.x & (NSHADOW - 1)) * (BB * HH);
        const int c = tid & 127, half = tid >> 7;
        const int row0 = half * 32;
        float sum = 0.f;
        int curg = -1;
        for (int r2 = 0; r2 < 32; ++r2) {
            int grow = brow + row0 + r2;
            if (grow >= M) break;
            int g = batch[grow];
            if (g != curg) {
                if (curg >= 0) atomicAdd(&pooled[curg * 128 + c], sum);
                curg = g; sum = 0.f;
            }
            sum += (float)smem[(row0 + r2) * 136 + c];
        }
        if (curg >= 0) atomicAdd(&pooled[curg * 128 + c], sum);
    }
}

// ---------------- Edge aggregation: fp16 gather-sum + per-node edge term -> fp16 ----------------
__global__ __launch_bounds__(256) void aggregate_k(
    const _Float16* __restrict__ h, const float* __restrict__ aggE,
    const float* __restrict__ eW, const float* __restrict__ eb,
    const int* __restrict__ rowstart, const int2* __restrict__ csr_pair,
    _Float16* __restrict__ Ag, int n)
{
    __shared__ float eWs[16 * 128];
    __shared__ float ebs[128];
    const int tid = threadIdx.x;
#pragma unroll
    for (int t = 0; t < 2; ++t) {
        int li = (tid + t * 256) * 4;
        *(float4*)(&eWs[li]) = *(const float4*)(eW + li);
    }
    if (tid < 32) *(float4*)(&ebs[tid * 4]) = *(const float4*)(eb + tid * 4);
    __syncthreads();

    const int lane = tid & 31;
    const int node = blockIdx.x * 8 + (tid >> 5);
    if (node >= n) return;
    const int s = rowstart[node], e = rowstart[node + 1];
    const f16x4* h4 = (const f16x4*)h;

    float4 acc = make_float4(0.f, 0.f, 0.f, 0.f);
    int p = s;
    for (; p + 4 <= e; p += 4) {
        int s0 = csr_pair[p].x, s1 = csr_pair[p + 1].x, s2 = csr_pair[p + 2].x, s3 = csr_pair[p + 3].x;
        f16x4 v0 = h4[(size_t)s0 * 32 + lane];
        f16x4 v1 = h4[(size_t)s1 * 32 + lane];
        f16x4 v2 = h4[(size_t)s2 * 32 + lane];
        f16x4 v3 = h4[(size_t)s3 * 32 + lane];
        acc.x += (float)v0[0] + (float)v1[0] + (float)v2[0] + (float)v3[0];
        acc.y += (float)v0[1] + (float)v1[1] + (float)v2[1] + (float)v3[1];
        acc.z += (float)v0[2] + (float)v1[2] + (float)v2[2] + (float)v3[2];
        acc.w += (float)v0[3] + (float)v1[3] + (float)v2[3] + (float)v3[3];
    }
    for (; p < e; ++p) {
        f16x4 v = h4[(size_t)csr_pair[p].x * 32 + lane];
        acc.x += (float)v[0]; acc.y += (float)v[1]; acc.z += (float)v[2]; acc.w += (float)v[3];
    }

    const float degf = (float)(e - s);
    const float* ae = aggE + (size_t)node * 16;
    const float4 b4 = *(const float4*)(&ebs[lane * 4]);
    float4 et = make_float4(degf * b4.x, degf * b4.y, degf * b4.z, degf * b4.w);
#pragma unroll
    for (int k = 0; k < 16; ++k) {
        float a = ae[k];
        float4 w = *(const float4*)(&eWs[k * 128 + lane * 4]);
        et.x = fmaf(a, w.x, et.x);
        et.y = fmaf(a, w.y, et.y);
        et.z = fmaf(a, w.z, et.z);
        et.w = fmaf(a, w.w, et.w);
    }
    acc.x += et.x; acc.y += et.y; acc.z += et.z; acc.w += et.w;

    f16x4 o;
    o[0] = (_Float16)acc.x; o[1] = (_Float16)acc.y; o[2] = (_Float16)acc.z; o[3] = (_Float16)acc.w;
    ((f16x4*)Ag)[(size_t)node * 32 + lane] = o;
}

// ---------------- aggE[n,16] = sum of eattr over in-edges ----------------
__global__ __launch_bounds__(256) void aggE_k(
    const float* __restrict__ eattr, const int* __restrict__ rowstart,
    const int2* __restrict__ csr_pair, float* __restrict__ aggE, int n)
{
    const int lane = threadIdx.x & 15;
    const int node = blockIdx.x * 16 + (threadIdx.x >> 4);
    if (node >= n) return;
    const int s = rowstart[node], e = rowstart[node + 1];
    float acc = 0.f;
    for (int p = s; p < e; ++p)
        acc += eattr[(size_t)csr_pair[p].y * 16 + lane];
    aggE[(size_t)node * 16 + lane] = acc;
}

// ---------------- VN update from shadowed pooled sums (also clears them) ----------------
__global__ __launch_bounds__(128) void vn_update_k(
    float* __restrict__ pooled8, const int* __restrict__ gstart,
    const float* __restrict__ W0, const float* __restrict__ b0,
    const float* __restrict__ W1, const float* __restrict__ b1,
    float* __restrict__ vn)
{
    __shared__ float p[128], q[128];
    const int g = blockIdx.x, t = threadIdx.x;
    float cnt = (float)(gstart[g + 1] - gstart[g]);
    if (cnt < 1.f) cnt = 1.f;
    float sum = 0.f;
#pragma unroll
    for (int s = 0; s < NSHADOW; ++s) {
        float* slot = pooled8 + (size_t)s * (BB * HH) + g * 128 + t;
        sum += *slot;
        *slot = 0.f;
    }
    p[t] = sum / cnt;
    __syncthreads();
    float a0 = b0[t];
    for (int k = 0; k < 128; ++k) a0 = fmaf(p[k], W0[k * 128 + t], a0);
    q[t] = fmaxf(a0, 0.f);
    __syncthreads();
    float a1 = b1[t];
    for (int k = 0; k < 128; ++k) a1 = fmaf(q[k], W1[k * 128 + t], a1);
    vn[g * 128 + t] += fmaxf(a1, 0.f);
}

// ---------------- final classifier from shadowed pooled sums ----------------
__global__ __launch_bounds__(128) void fc_k(
    const float* __restrict__ pooled8, const int* __restrict__ gstart,
    const float* __restrict__ W, const float* __restrict__ b,
    float* __restrict__ out)
{
    __shared__ float p[128];
    const int g = blockIdx.x, t = threadIdx.x;
    float cnt = (float)(gstart[g + 1] - gstart[g]);
    if (cnt < 1.f) cnt = 1.f;
    float sum = 0.f;
#pragma unroll
    for (int s = 0; s < NSHADOW; ++s)
        sum += pooled8[(size_t)s * (BB * HH) + g * 128 + t];
    p[t] = sum / cnt;
    __syncthreads();
    float acc = b[t];
    for (int k = 0; k < 128; ++k) acc = fmaf(p[k], W[k * 128 + t], acc);
    out[g * 128 + t] = acc;
}

// ---------------- CSR build helpers ----------------
__global__ void histp_k(const int* __restrict__ idx, int n, int* __restrict__ cntp)
{
    int i = blockIdx.x * 256 + threadIdx.x;
    if (i < n) atomicAdd(&cntp[(blockIdx.x & 3) * NN16 + (idx[i] << 4)], 1);
}

__global__ void scan_deg_k(const int* __restrict__ degp, int n, int* __restrict__ out, int* __restrict__ bsum)
{
    __shared__ int s[256];
    int gid = blockIdx.x * 256 + threadIdx.x;
    int v = 0;
    if (gid < n) {
        int o = gid << 4;
        v = degp[o] + degp[NN16 + o] + degp[2 * NN16 + o] + degp[3 * NN16 + o];
    }
    s[threadIdx.x] = v;
    __syncthreads();
    for (int off = 1; off < 256; off <<= 1) {
        int t = (threadIdx.x >= off) ? s[threadIdx.x - off] : 0;
        __syncthreads();
        s[threadIdx.x] += t;
        __syncthreads();
    }
    int incl = s[threadIdx.x];
    if (gid < n) out[gid] = incl - v;
    if (bsum != nullptr && threadIdx.x == 255) bsum[blockIdx.x] = incl;
}

__global__ void scan_k(const int* __restrict__ in, int n, int* __restrict__ out, int* __restrict__ bsum)
{
    __shared__ int s[256];
    int gid = blockIdx.x * 256 + threadIdx.x;
    int v = (gid < n) ? in[gid] : 0;
    s[threadIdx.x] = v;
    __syncthreads();
    for (int off = 1; off < 256; off <<= 1) {
        int t = (threadIdx.x >= off) ? s[threadIdx.x - off] : 0;
        __syncthreads();
        s[threadIdx.x] += t;
        __syncthreads();
    }
    int incl = s[threadIdx.x];
    if (gid < n) out[gid] = incl - v;
    if (bsum != nullptr && threadIdx.x == 255) bsum[blockIdx.x] = incl;
}

__global__ void addoff_k(int* __restrict__ data, const int* __restrict__ boff, int n, int total)
{
    int i = blockIdx.x * 256 + threadIdx.x;
    if (i < n) data[i] += boff[blockIdx.x];
    if (i == 0) data[n] = total;
}

__global__ void curinit_k(const int* __restrict__ rowstart, int* __restrict__ cursorp)
{
    int i = blockIdx.x * 256 + threadIdx.x;
    if (i < NN) cursorp[i << 4] = rowstart[i];
}

__global__ void fill_k(const int* __restrict__ dst, const int* __restrict__ src, int n,
                       int* __restrict__ cursorp, int2* __restrict__ csr_pair)
{
    int e = blockIdx.x * 256 + threadIdx.x;
    if (e < n) {
        int slot = atomicAdd(&cursorp[dst[e] << 4], 1);
        int2 pr; pr.x = src[e]; pr.y = e;
        csr_pair[slot] = pr;
    }
}

__global__ void gstart_k(const int* __restrict__ batch, int* __restrict__ gstart)
{
    int b = blockIdx.x * 64 + threadIdx.x;
    if (b > BB) return;
    if (b == BB) { gstart[BB] = NN; return; }
    int lo = 0, hi = NN;
    while (lo < hi) {
        int mid = (lo + hi) >> 1;
        if (batch[mid] < b) lo = mid + 1; else hi = mid;
    }
    gstart[b] = lo;
}

__global__ void vninit_k(const float* __restrict__ vninit, float* __restrict__ vn, float* __restrict__ pooled8)
{
    int i = blockIdx.x * 256 + threadIdx.x;
    if (i < BB * HH) vn[i] = vninit[i & 127];
    if (i < NSHADOW * BB * HH) pooled8[i] = 0.f;
}

// ---------------- Launch ----------------
extern "C" void kernel_launch(void* const* d_in, const int* in_sizes, int n_in,
                              void* d_out, int out_size, void* d_ws, size_t ws_size,
                              hipStream_t stream)
{
    (void)in_sizes; (void)n_in; (void)out_size; (void)ws_size;
    const float* x       = (const float*)d_in[0];
    const float* eattr   = (const float*)d_in[1];
    const float* node_W  = (const float*)d_in[2];
    const float* node_b  = (const float*)d_in[3];
    const float* edge_W  = (const float*)d_in[4];
    const float* edge_b  = (const float*)d_in[5];
    const float* mlp1_W  = (const float*)d_in[6];
    const float* mlp1_b  = (const float*)d_in[7];
    const float* mlp2_W  = (const float*)d_in[8];
    const float* mlp2_b  = (const float*)d_in[9];
    const float* vn_w0   = (const float*)d_in[10];
    const float* vn_b0   = (const float*)d_in[11];
    const float* vn_w1   = (const float*)d_in[12];
    const float* vn_b1   = (const float*)d_in[13];
    const float* fc_W    = (const float*)d_in[14];
    const float* fc_b    = (const float*)d_in[15];
    const float* vn_init = (const float*)d_in[16];
    const int*   eidx    = (const int*)d_in[17];
    const int*   batch   = (const int*)d_in[18];
    const int* srcv = eidx;
    const int* dstv = eidx + EE;

    char* wp = (char*)d_ws;
    auto alloc = [&](size_t bytes) -> void* {
        void* p = (void*)wp;
        wp += (bytes + 255) & ~(size_t)255;
        return p;
    };
    _Float16* X0  = (_Float16*)alloc((size_t)NN * HH * 2);
    _Float16* X   = (_Float16*)alloc((size_t)NN * HH * 2);
    _Float16* Ag  = (_Float16*)alloc((size_t)NN * HH * 2);
    _Float16* h16 = (_Float16*)alloc((size_t)NN * HH * 2);
    float* aggE   = (float*)alloc((size_t)NN * EDD * 4);
    float* vn     = (float*)alloc((size_t)BB * HH * 4);
    float* pooled8= (float*)alloc((size_t)NSHADOW * BB * HH * 4);
    int* degp     = (int*)alloc((size_t)4 * NN16 * 4);
    int* rowstart = (int*)alloc((size_t)(NN + 1) * 4);
    int* cursorp  = (int*)alloc((size_t)NN16 * 4);
    int2* csr_pair= (int2*)alloc((size_t)EE * 8);
    int* bsum     = (int*)alloc(256 * 4);
    int* boff     = (int*)alloc(256 * 4);
    int* gstart   = (int*)alloc((size_t)(BB + 1) * 4);
    _Float16* WtN_h = (_Float16*)alloc((size_t)5 * 16384 * 2);
    _Float16* WtN_l = (_Float16*)alloc((size_t)5 * 16384 * 2);
    _Float16* Wt1_h = (_Float16*)alloc((size_t)5 * 16384 * 2);
    _Float16* Wt1_l = (_Float16*)alloc((size_t)5 * 16384 * 2);
    _Float16* Wt2_h = (_Float16*)alloc((size_t)5 * 16384 * 2);
    _Float16* Wt2_l = (_Float16*)alloc((size_t)5 * 16384 * 2);

    hipMemsetAsync(degp, 0, (size_t)4 * NN16 * 4, stream);

    histp_k<<<(EE + 255) / 256, 256, 0, stream>>>(dstv, EE, degp);

    const int NB1 = (NN + 255) / 256;
    scan_deg_k<<<NB1, 256, 0, stream>>>(degp, NN, rowstart, bsum);
    scan_k<<<1, 256, 0, stream>>>(bsum, NB1, boff, nullptr);
    addoff_k<<<NB1, 256, 0, stream>>>(rowstart, boff, NN, EE);
    curinit_k<<<NB1, 256, 0, stream>>>(rowstart, cursorp);
    fill_k<<<(EE + 255) / 256, 256, 0, stream>>>(dstv, srcv, EE, cursorp, csr_pair);

    gstart_k<<<5, 64, 0, stream>>>(batch, gstart);

    aggE_k<<<(NN + 15) / 16, 256, 0, stream>>>(eattr, rowstart, csr_pair, aggE, NN);
    vninit_k<<<(NSHADOW * BB * HH) / 256, 256, 0, stream>>>(vn_init, vn, pooled8);
    xprep_k<<<(NN * 32 + 255) / 256, 256, 0, stream>>>(x, X0);

    wprep_k<<<(5 * 16384 + 255) / 256, 256, 0, stream>>>(node_W, WtN_h, WtN_l, 5 * 16384);
    wprep_k<<<(5 * 16384 + 255) / 256, 256, 0, stream>>>(mlp1_W, Wt1_h, Wt1_l, 5 * 16384);
    wprep_k<<<(5 * 16384 + 255) / 256, 256, 0, stream>>>(mlp2_W, Wt2_h, Wt2_l, 5 * 16384);

    const int GN = (NN + 63) / 64;
    const _Float16* xin = X0;
    for (int l = 0; l < LL; ++l) {
        gemm_node_k<<<GN, 256, 0, stream>>>(xin,
                                            WtN_h + (size_t)l * 16384, WtN_l + (size_t)l * 16384,
                                            node_b + (size_t)l * HH, h16, NN, vn, batch);
        aggregate_k<<<(NN + 7) / 8, 256, 0, stream>>>(h16, aggE, edge_W + (size_t)l * EDD * HH,
                                                      edge_b + (size_t)l * HH, rowstart, csr_pair, Ag, NN);
        gemm_mlp_k<<<GN, 256, 0, stream>>>(Ag,
                                           Wt1_h + (size_t)l * 16384, Wt1_l + (size_t)l * 16384, mlp1_b + (size_t)l * HH,
                                           Wt2_h + (size_t)l * 16384, Wt2_l + (size_t)l * 16384, mlp2_b + (size_t)l * HH,
                                           X, pooled8, batch, NN);
        if (l < LL - 1)
            vn_update_k<<<BB, 128, 0, stream>>>(pooled8, gstart, vn_w0, vn_b0, vn_w1, vn_b1, vn);
        xin = X;
    }
    fc_k<<<BB, 128, 0, stream>>>(pooled8, gstart, fc_W, fc_b, (float*)d_out);
}